// Round 6
// baseline (350.165 us; speedup 1.0000x reference)
//
#include <hip/hip_runtime.h>
#include <hip/hip_bf16.h>

#define NEGINF -1e30f

typedef __attribute__((ext_vector_type(8))) short short8;
typedef __attribute__((ext_vector_type(4))) float f32x4;
typedef __attribute__((ext_vector_type(4))) int int4_t;

// Clamp-free: IEEE inf semantics give exact limits (exp->inf => rcp->0), NaN-free.
__device__ __forceinline__ float fast_sigmoid(float x) {
    return __builtin_amdgcn_rcpf(1.f + __expf(-x));
}
// round-to-nearest-even f32 -> bf16 bits
__device__ __forceinline__ short f2bf(float f) {
    unsigned u = __float_as_uint(f);
    return (short)((u + 0x7fff + ((u >> 16) & 1)) >> 16);
}
__device__ __forceinline__ float bf2f(short b) {
    return __uint_as_float(((unsigned)(unsigned short)b) << 16);
}

// LDS-only workgroup barrier (proven R3-R20): waits lgkmcnt only; in-flight global
// loads/stores are NOT drained. Safe when all cross-thread traffic goes through LDS.
__device__ __forceinline__ void bar_lds() {
    asm volatile("s_waitcnt lgkmcnt(0)\n\ts_barrier" ::: "memory");
}

// ---------------- MFMA GEMM (R12, known-good): out = A @ W^T + bias ------------------
__global__ __launch_bounds__(256) void gemm_bias(
    const float* __restrict__ A,
    const float* __restrict__ W1, const float* __restrict__ b1, float* __restrict__ out1,
    const float* __restrict__ W2, const float* __restrict__ b2, float* __restrict__ out2,
    const int* __restrict__ lengths,
    int M, int N, int K, int nsplit, int mode) {
    const int m0 = blockIdx.y * 64;
    if ((m0 & 511) >= lengths[m0 >> 9]) return;  // uniform per block; rows unread
    __shared__ __align__(16) short Abh[2][2048];
    __shared__ __align__(16) short Abl[2][2048];
    __shared__ __align__(16) short Bbh[2][2048];
    __shared__ __align__(16) short Bbl[2][2048];
    const int tid = threadIdx.x;
    int bx = blockIdx.x;
    const float* W = W1; const float* bias = b1; float* out = out1;
    int n0;
    if (bx < nsplit) {
        n0 = bx * 64;
    } else {
        W = W2; bias = b2; out = out2;
        n0 = (bx - nsplit) * 64;
    }
    const int wave = tid >> 6;
    const int lane = tid & 63;
    const int mrow = lane & 15;
    const int quad = lane >> 4;
    const int wm = (wave >> 1) * 32;
    const int wn = (wave & 1) * 32;

    const int r_ = tid >> 2;
    const int sg = (tid & 3) * 8;

    f32x4 acc[2][2];
#pragma unroll
    for (int mt = 0; mt < 2; mt++)
#pragma unroll
        for (int nt = 0; nt < 2; nt++) acc[mt][nt] = (f32x4){0.f, 0.f, 0.f, 0.f};

    float4 a0 = *(const float4*)(A + (size_t)(m0 + r_) * K + sg);
    float4 a1 = *(const float4*)(A + (size_t)(m0 + r_) * K + sg + 4);
    float4 w0 = *(const float4*)(W + (size_t)(n0 + r_) * K + sg);
    float4 w1 = *(const float4*)(W + (size_t)(n0 + r_) * K + sg + 4);

    for (int k0 = 0; k0 < K; k0 += 32) {
        const int cur = (k0 >> 5) & 1;
        {
            float av[8] = {a0.x, a0.y, a0.z, a0.w, a1.x, a1.y, a1.z, a1.w};
            float wv[8] = {w0.x, w0.y, w0.z, w0.w, w1.x, w1.y, w1.z, w1.w};
            short8 ah, al, bh, bl;
#pragma unroll
            for (int j = 0; j < 8; j++) {
                short h = f2bf(av[j]); ah[j] = h; al[j] = f2bf(av[j] - bf2f(h));
                short g = f2bf(wv[j]); bh[j] = g; bl[j] = f2bf(wv[j] - bf2f(g));
            }
            *(short8*)&Abh[cur][r_ * 32 + sg] = ah;
            *(short8*)&Abl[cur][r_ * 32 + sg] = al;
            *(short8*)&Bbh[cur][r_ * 32 + sg] = bh;
            *(short8*)&Bbl[cur][r_ * 32 + sg] = bl;
        }
        if (k0 + 32 < K) {
            a0 = *(const float4*)(A + (size_t)(m0 + r_) * K + k0 + 32 + sg);
            a1 = *(const float4*)(A + (size_t)(m0 + r_) * K + k0 + 32 + sg + 4);
            w0 = *(const float4*)(W + (size_t)(n0 + r_) * K + k0 + 32 + sg);
            w1 = *(const float4*)(W + (size_t)(n0 + r_) * K + k0 + 32 + sg + 4);
        }
        bar_lds();
        short8 Ah[2], Al[2], Bh[2], Bl[2];
#pragma unroll
        for (int t = 0; t < 2; t++) {
            int ar = (wm + t * 16 + mrow) * 32 + quad * 8;
            int br = (wn + t * 16 + mrow) * 32 + quad * 8;
            Ah[t] = *(const short8*)&Abh[cur][ar];
            Al[t] = *(const short8*)&Abl[cur][ar];
            Bh[t] = *(const short8*)&Bbh[cur][br];
            Bl[t] = *(const short8*)&Bbl[cur][br];
        }
#pragma unroll
        for (int mt = 0; mt < 2; mt++)
#pragma unroll
            for (int nt = 0; nt < 2; nt++) {
                acc[mt][nt] = __builtin_amdgcn_mfma_f32_16x16x32_bf16(Ah[mt], Bh[nt], acc[mt][nt], 0, 0, 0);
                acc[mt][nt] = __builtin_amdgcn_mfma_f32_16x16x32_bf16(Al[mt], Bh[nt], acc[mt][nt], 0, 0, 0);
                acc[mt][nt] = __builtin_amdgcn_mfma_f32_16x16x32_bf16(Ah[mt], Bl[nt], acc[mt][nt], 0, 0, 0);
            }
        bar_lds();
    }
    float bsv[2];
#pragma unroll
    for (int nt = 0; nt < 2; nt++) bsv[nt] = bias[n0 + wn + nt * 16 + mrow];
#pragma unroll
    for (int mt = 0; mt < 2; mt++)
#pragma unroll
        for (int nt = 0; nt < 2; nt++) {
            int n = n0 + wn + nt * 16 + mrow;
#pragma unroll
            for (int r = 0; r < 4; r++) {
                int m = m0 + wm + mt * 16 + quad * 4 + r;
                float val = acc[mt][nt][r] + bsv[nt];
                if (mode == 1) val = fast_sigmoid(val) * A[(size_t)m * K + n];
                out[(size_t)m * N + n] = val;
            }
        }
}

// ---------------- Attention, 8 queries per block (R12, known-good) -------------------
__global__ __launch_bounds__(512) void attn_kernel(
    const float* __restrict__ v, const int* __restrict__ lengths,
    const float* __restrict__ own, const float* __restrict__ comp,
    const float* __restrict__ v_attn, float* __restrict__ inp) {
    const int L = 512, D = 256, H = 128;
    const int b = blockIdx.x >> 6;
    const int q0 = (blockIdx.x & 63) * 8;
    const int len = lengths[b];
    if (q0 >= len) return;
    const int tid = threadIdx.x;
    const float K2E = 2.8853900817779268f;  // 2*log2(e)
    __shared__ __align__(16) float oKT[128 * 8];
    __shared__ float va2s[128];
    __shared__ __align__(16) float scf[512 * 12];
    __shared__ float inv8[8];

    for (int i = tid; i < 1024; i += 512) {
        int qq = i >> 7, hh = i & 127;
        oKT[hh * 8 + qq] = K2E * own[((size_t)(b * L + q0 + qq)) * H + hh];
    }
    if (tid < 128) va2s[tid] = -2.f * v_attn[tid];
    __syncthreads();

    {
        const int k = tid;
        float acc[8];
#pragma unroll
        for (int q = 0; q < 8; q++) acc[q] = 0.f;
        if (k < len) {
            const float* cp = comp + ((size_t)(b * L + k)) * H;
            for (int h = 0; h < 128; h += 4) {
                float4 c4 = *(const float4*)(cp + h);
                const float* cv = (const float*)&c4;
#pragma unroll
                for (int j = 0; j < 4; j++) {
                    float cK = cv[j] * K2E;
                    float va = va2s[h + j];
                    float4 o0 = *(const float4*)&oKT[(h + j) * 8];
                    float4 o1 = *(const float4*)&oKT[(h + j) * 8 + 4];
                    const float* op0 = (const float*)&o0;
                    const float* op1 = (const float*)&o1;
#pragma unroll
                    for (int q = 0; q < 4; q++) {
                        float r = __builtin_amdgcn_rcpf(1.f + exp2f(cK + op0[q]));
                        acc[q] = fmaf(va, r, acc[q]);
                    }
#pragma unroll
                    for (int q = 0; q < 4; q++) {
                        float r = __builtin_amdgcn_rcpf(1.f + exp2f(cK + op1[q]));
                        acc[4 + q] = fmaf(va, r, acc[4 + q]);
                    }
                }
            }
#pragma unroll
            for (int q = 0; q < 8; q++) acc[q] = __expf(acc[q]);  // bounded, no max pass
        }
        *(float4*)&scf[k * 12] = *(float4*)&acc[0];
        *(float4*)&scf[k * 12 + 4] = *(float4*)&acc[4];
    }
    __syncthreads();

    {
        int w = tid >> 6, l = tid & 63;
        float s = 0.f;
#pragma unroll
        for (int kk = 0; kk < 8; kk++) s += scf[(l + kk * 64) * 12 + w];
#pragma unroll
        for (int off = 1; off < 64; off <<= 1) s += __shfl_xor(s, off);
        if (l == 0) inv8[w] = __builtin_amdgcn_rcpf(s);
    }
    __syncthreads();

    {
        const int d = tid & 255;
        const int qh = tid >> 8;
        float c0 = 0.f, c1 = 0.f, c2 = 0.f, c3 = 0.f;
        const float* vb = v + ((size_t)b * L) * D + d;
        for (int k = 0; k < L; k += 2) {
            float v0 = vb[(size_t)k * D];
            float v1 = vb[(size_t)(k + 1) * D];
            float4 s0 = *(const float4*)&scf[k * 12 + qh * 4];
            float4 s1 = *(const float4*)&scf[(k + 1) * 12 + qh * 4];
            c0 += s0.x * v0 + s1.x * v1;
            c1 += s0.y * v0 + s1.y * v1;
            c2 += s0.z * v0 + s1.z * v1;
            c3 += s0.w * v0 + s1.w * v1;
        }
        float cc[4] = {c0, c1, c2, c3};
#pragma unroll
        for (int j = 0; j < 4; j++) {
            int q = q0 + qh * 4 + j;
            size_t row = ((size_t)(b * L + q)) * 512;
            inp[row + 256 + d] = cc[j] * inv8[qh * 4 + j];
            inp[row + d] = v[((size_t)(b * L + q)) * D + d];
        }
    }
}

// ---------------- GRU recurrence: i8 MFMA K=64 (R20 + slim step window) --------------
// R21 = R20 (proven: use-free prefetch loads, fold-at-rotate, native exp2 slim chain,
// magic-number RNE quantize — gru 156us) + two issue-slot cuts in the barrier-to-
// barrier step window, no change to load schedule / LDS layout / math:
//  1. Deferred out-stores: hn buffered in hsv[16] registers, stored once per chunk
//     at the chunk boundary (overlaps prefetch drain + rotate). Removes the
//     global_store + ~5 addr-VALU from every step window.
//  2. Full/tail chunk split: full chunks (cnt==16, block-uniform) run an
//     unpredicated 16-step body — drops per-step s_cmp+branch and lets the
//     scheduler pack the window tighter. Tail chunk keeps the predicated form.
// h: Q0.13 = hi*64 + lo (two i8 A rows; integer dot EXACT). W_hh: per-row i8 +
// row scale. hbuf: hi at byte 0, lo at byte 192 (word 48 === 16 mod 32): disjoint
// 16-bank halves. Single lgkmcnt-only barrier per step. 8 waves (2/SIMD — R17
// proved 1 wave/SIMD loses ~400cy/step of MFMA<->VALU<->LDS overlap).
__global__ __launch_bounds__(512, 1) void gru_kernel(
    const float* __restrict__ xp_f, const float* __restrict__ xp_b,
    const float* __restrict__ w_hh_f, const float* __restrict__ w_hh_b,
    const float* __restrict__ b_hh_f, const float* __restrict__ b_hh_b,
    const int* __restrict__ lengths, float* __restrict__ out) {
    const int L = 512, H = 128;
    const float LOG2E = 1.4426950408889634f;
    const float TWO_LOG2E = 2.8853900817779268f;
    const int MAGIC_I = 0x4B400000;  // bits of 12582912.0f = 1.5*2^23
    const int dir = blockIdx.x >> 2;
    const int b = blockIdx.x & 3;
    const float* xp = dir ? xp_b : xp_f;
    const float* w_hh = dir ? w_hh_b : w_hh_f;
    const float* b_hh = dir ? b_hh_b : b_hh_f;
    const int tid = threadIdx.x;
    const int wave = tid >> 6;
    const int lane = tid & 63;
    const int mrow = lane & 15;
    const int quad = lane >> 4;
    const int jj = 16 * wave + lane;  // gate dim for lanes lane<16

    // [parity][ h_hi bytes 0..127 | pad | h_lo bytes 192..319 | pad..383 ]
    __shared__ __align__(16) signed char hbufc[2][384];

    // ---- W_hh -> per-row i8 + scale. Lane (mrow,quad) holds B[k=kt*64+quad*16+j][row]
    // for rows g*128 + 16*wave + mrow; row max reduced across the 4 quads via shfl. ----
    int4_t wb[3][2];
    float wsc0, wsc1, wsc2;  // dequant scales with exp2-conversion factors folded in
    {
        float wsl[3];
#pragma unroll
        for (int g = 0; g < 3; g++) {
            int row = g * 128 + 16 * wave + mrow;
            float wv[32];
#pragma unroll
            for (int kt = 0; kt < 2; kt++)
#pragma unroll
                for (int j4 = 0; j4 < 4; j4++) {
                    float4 f4 = *(const float4*)(w_hh + (size_t)row * H + kt * 64 + quad * 16 + j4 * 4);
                    wv[kt * 16 + j4 * 4 + 0] = f4.x;
                    wv[kt * 16 + j4 * 4 + 1] = f4.y;
                    wv[kt * 16 + j4 * 4 + 2] = f4.z;
                    wv[kt * 16 + j4 * 4 + 3] = f4.w;
                }
            float mx = 0.f;
#pragma unroll
            for (int j = 0; j < 32; j++) mx = fmaxf(mx, fabsf(wv[j]));
            mx = fmaxf(mx, __shfl_xor(mx, 16));
            mx = fmaxf(mx, __shfl_xor(mx, 32));
            mx = fmaxf(mx, 1e-30f);
            float inv_s = 127.f / mx;
            wsl[g] = (mx / 127.f) * (1.f / 8192.f);
#pragma unroll
            for (int kt = 0; kt < 2; kt++) {
                int tmp[4] = {0, 0, 0, 0};
#pragma unroll
                for (int j = 0; j < 16; j++) {
                    int q = (int)rintf(wv[kt * 16 + j] * inv_s);
                    tmp[j >> 2] |= (q & 0xff) << ((j & 3) * 8);
                }
                wb[g][kt] = (int4_t){tmp[0], tmp[1], tmp[2], tmp[3]};
            }
        }
        // fold exp2 conversion: r,z use -(arg)*log2e ; n uses (arg)*2log2e
        wsc0 = -wsl[0] * LOG2E;
        wsc1 = -wsl[1] * LOG2E;
        wsc2 = wsl[2] * TWO_LOG2E;
    }
    float brl = 0.f, bzl = 0.f, bnc = 0.f, hcur = 0.f;
    if (lane < 16) {
        brl = -b_hh[jj] * LOG2E;
        bzl = -b_hh[128 + jj] * LOG2E;
        bnc = b_hh[256 + jj] * TWO_LOG2E;
    }

    const int len = lengths[b];
    // pre-zero masked tail: out[b, t, dir*128+k] = 0 for t in [len, L)
    for (int i = tid; i < (L - len) * 128; i += 512) {
        int tt = len + (i >> 7);
        int kk = i & 127;
        out[((size_t)(b * L + tt)) * 256 + dir * 128 + kk] = 0.f;
    }
    for (int i = tid; i < 768; i += 512) ((signed char*)hbufc)[i] = 0;

    const int nch = (len + 15) >> 4;
    // gate-lane xp registers for the current chunk: RAW loads (use-free, R16-exact),
    // then fold bias + exp2-conversion in place (one-time; off the step chain).
    float xr[16], xz[16], xn[16];
    if (lane < 16) {
#pragma unroll
        for (int s = 0; s < 16; s++) {
            if (s < len) {
                int t = dir ? (len - 1 - s) : s;
                size_t base = ((size_t)(b * L + t)) * 384;
                xr[s] = xp[base + jj];
                xz[s] = xp[base + 128 + jj];
                xn[s] = xp[base + 256 + jj];
            }
        }
#pragma unroll
        for (int s = 0; s < 16; s++) {
            xr[s] = fmaf(xr[s], -LOG2E, brl);
            xz[s] = fmaf(xz[s], -LOG2E, bzl);
            xn[s] = xn[s] * TWO_LOG2E;
        }
    }
    __syncthreads();

    // A-frag byte base: row0 (h_hi) at 0, row1 (h_lo) at 192; rows 2-15 duplicates
    const int bbase = ((mrow & 1) ? 192 : 0) + quad * 16;
    int par = 0;

// one GRU timestep: ds_read A-frags, 6 MFMA, gate math, h write, barrier.
// Out-store deferred to chunk end via hsv (issue-slot cut #1).
#define GRU_STEP(s)                                                                                   \
    {                                                                                                 \
        int4_t af0 = *(const int4_t*)&hbufc[par][bbase];                                              \
        int4_t af1 = *(const int4_t*)&hbufc[par][bbase + 64];                                         \
        int4_t a0 = (int4_t){0, 0, 0, 0};                                                             \
        int4_t a1 = (int4_t){0, 0, 0, 0};                                                             \
        int4_t a2 = (int4_t){0, 0, 0, 0};                                                             \
        a0 = __builtin_amdgcn_mfma_i32_16x16x64_i8(af0, wb[0][0], a0, 0, 0, 0);                       \
        a0 = __builtin_amdgcn_mfma_i32_16x16x64_i8(af1, wb[0][1], a0, 0, 0, 0);                       \
        a1 = __builtin_amdgcn_mfma_i32_16x16x64_i8(af0, wb[1][0], a1, 0, 0, 0);                       \
        a1 = __builtin_amdgcn_mfma_i32_16x16x64_i8(af1, wb[1][1], a1, 0, 0, 0);                       \
        a2 = __builtin_amdgcn_mfma_i32_16x16x64_i8(af0, wb[2][0], a2, 0, 0, 0);                       \
        a2 = __builtin_amdgcn_mfma_i32_16x16x64_i8(af1, wb[2][1], a2, 0, 0, 0);                       \
        if (lane < 16) {                                                                              \
            float drf = (float)(a0[0] * 64 + a0[1]);                                                  \
            float dzf = (float)(a1[0] * 64 + a1[1]);                                                  \
            float dnf = (float)(a2[0] * 64 + a2[1]);                                                  \
            float r = __builtin_amdgcn_rcpf(1.f + __builtin_amdgcn_exp2f(fmaf(drf, wsc0, xr[s])));    \
            float z = __builtin_amdgcn_rcpf(1.f + __builtin_amdgcn_exp2f(fmaf(dzf, wsc1, xz[s])));    \
            float hh = fmaf(dnf, wsc2, bnc);                                                          \
            float n = fmaf(-2.f, __builtin_amdgcn_rcpf(1.f + __builtin_amdgcn_exp2f(fmaf(r, hh, xn[s]))), 1.f); \
            float hn = fmaf(z, hcur - n, n);                                                          \
            hcur = hn;                                                                                \
            int bi = __float_as_int(fmaf(hn, 8192.f, 12582912.f));                                    \
            bi = min(max(bi, MAGIC_I - 8191), MAGIC_I + 8191);                                        \
            hbufc[par ^ 1][jj] = (signed char)(bi >> 6);                                              \
            hbufc[par ^ 1][192 + jj] = (signed char)(bi & 63);                                        \
            hsv[s] = hn;                                                                              \
        }                                                                                             \
        par ^= 1;                                                                                     \
        bar_lds();                                                                                    \
    }

    for (int c = 0; c < nch; c++) {
        const int cnt = min(16, len - c * 16);
        // prefetch chunk c+1 into a second register set (RAW loads, no use here);
        // vmcnt waits land at the rotate, a full chunk (~12000 cy) later
        float nxr[16], nxz[16], nxn[16];
        if (lane < 16 && c + 1 < nch) {
#pragma unroll
            for (int s = 0; s < 16; s++) {
                int rr = (c + 1) * 16 + s;
                if (rr < len) {
                    int t = dir ? (len - 1 - rr) : rr;
                    size_t base = ((size_t)(b * L + t)) * 384;
                    nxr[s] = xp[base + jj];
                    nxz[s] = xp[base + 128 + jj];
                    nxn[s] = xp[base + 256 + jj];
                }
            }
        }
        float hsv[16];
        if (cnt == 16) {  // block-uniform: full chunk, unpredicated body (cut #2)
#pragma unroll
            for (int s = 0; s < 16; s++) GRU_STEP(s)
        } else {          // tail chunk (runs at most once per block)
#pragma unroll
            for (int s = 0; s < 16; s++)
                if (s < cnt) GRU_STEP(s)
        }
        // deferred fire-and-forget out stores for this chunk (off the step chain;
        // overlaps the prefetch vmcnt drain and the rotate)
        if (lane < 16) {
#pragma unroll
            for (int s = 0; s < 16; s++) {
                if (s < cnt) {
                    int step = c * 16 + s;
                    int t = dir ? (len - 1 - step) : step;
                    out[((size_t)(b * L + t)) * 256 + dir * 128 + jj] = hsv[s];
                }
            }
        }
        // rotate prefetched chunk into place WITH folding (vmcnt wait lands here,
        // a full chunk later; the 48 fmas are once-per-chunk, off the step chain)
        if (lane < 16 && c + 1 < nch) {
#pragma unroll
            for (int s = 0; s < 16; s++) {
                xr[s] = fmaf(nxr[s], -LOG2E, brl);
                xz[s] = fmaf(nxz[s], -LOG2E, bzl);
                xn[s] = nxn[s] * TWO_LOG2E;
            }
        }
    }
#undef GRU_STEP
}

extern "C" void kernel_launch(void* const* d_in, const int* in_sizes, int n_in,
                              void* d_out, int out_size, void* d_ws, size_t ws_size,
                              hipStream_t stream) {
    const int B = 4, L = 512, D = 256, H = 128;
    const int M = B * L;  // 2048

    const float* v      = (const float*)d_in[0];
    const int* lengths  = (const int*)d_in[1];
    const float* own_W  = (const float*)d_in[3];
    const float* own_b  = (const float*)d_in[4];
    const float* comp_W = (const float*)d_in[5];
    const float* comp_b = (const float*)d_in[6];
    const float* v_attn = (const float*)d_in[7];
    const float* gate_W = (const float*)d_in[8];
    const float* gate_b = (const float*)d_in[9];
    const float* w_ih_f = (const float*)d_in[10];
    const float* w_hh_f = (const float*)d_in[11];
    const float* b_ih_f = (const float*)d_in[12];
    const float* b_hh_f = (const float*)d_in[13];
    const float* w_ih_b = (const float*)d_in[14];
    const float* w_hh_b = (const float*)d_in[15];
    const float* b_ih_b = (const float*)d_in[16];
    const float* b_hh_b = (const float*)d_in[17];

    float* ws   = (float*)d_ws;
    float* own  = ws;                       // [2048,128]
    float* comp = own + (size_t)M * H;      // [2048,128]
    float* inp  = comp + (size_t)M * H;     // [2048,512]
    float* gated = inp + (size_t)M * 512;   // [2048,512]
    float* xp_f = gated + (size_t)M * 512;  // [2048,384]
    float* xp_b = xp_f + (size_t)M * 384;   // [2048,384]
    float* out  = (float*)d_out;            // [2048,256]

    // 1: own & comp projections in one launch (tiles 0..1 -> own, 2..3 -> comp)
    gemm_bias<<<dim3(4, M / 64), 256, 0, stream>>>(
        v, own_W, own_b, own, comp_W, comp_b, comp, lengths, M, H, D, 2, 0);
    // 2: attention (8 q per block) -> inp = [v, C]
    attn_kernel<<<dim3(B * 64), 512, 0, stream>>>(v, lengths, own, comp, v_attn, inp);
    // 3: gate
    gemm_bias<<<dim3(8, M / 64), 256, 0, stream>>>(
        inp, gate_W, gate_b, gated, gate_W, gate_b, gated, lengths, M, 512, 512, 8, 1);
    // 4: input projections for both GRU directions in one launch
    gemm_bias<<<dim3(12, M / 64), 256, 0, stream>>>(
        gated, w_ih_f, b_ih_f, xp_f, w_ih_b, b_ih_b, xp_b, lengths, M, 384, 512, 6, 0);
    // 5: sequential GRU, one block per (dir, batch), 8 waves (2/SIMD)
    gru_kernel<<<dim3(8), 512, 0, stream>>>(xp_f, xp_b, w_hh_f, w_hh_b, b_hh_f, b_hh_b, lengths, out);
}

// Round 7
// 347.104 us; speedup vs baseline: 1.0088x; 1.0088x over previous
//
#include <hip/hip_runtime.h>
#include <hip/hip_bf16.h>

#define NEGINF -1e30f

typedef __attribute__((ext_vector_type(8))) short short8;
typedef __attribute__((ext_vector_type(4))) float f32x4;
typedef __attribute__((ext_vector_type(4))) int int4_t;

// Clamp-free: IEEE inf semantics give exact limits (exp->inf => rcp->0), NaN-free.
__device__ __forceinline__ float fast_sigmoid(float x) {
    return __builtin_amdgcn_rcpf(1.f + __expf(-x));
}
// round-to-nearest-even f32 -> bf16 bits
__device__ __forceinline__ short f2bf(float f) {
    unsigned u = __float_as_uint(f);
    return (short)((u + 0x7fff + ((u >> 16) & 1)) >> 16);
}
__device__ __forceinline__ float bf2f(short b) {
    return __uint_as_float(((unsigned)(unsigned short)b) << 16);
}

// LDS-only workgroup barrier (proven R3-R20): waits lgkmcnt only; in-flight global
// loads/stores are NOT drained. Safe when all cross-thread traffic goes through LDS.
__device__ __forceinline__ void bar_lds() {
    asm volatile("s_waitcnt lgkmcnt(0)\n\ts_barrier" ::: "memory");
}

// ---------------- MFMA GEMM (R12, known-good): out = A @ W^T + bias ------------------
__global__ __launch_bounds__(256) void gemm_bias(
    const float* __restrict__ A,
    const float* __restrict__ W1, const float* __restrict__ b1, float* __restrict__ out1,
    const float* __restrict__ W2, const float* __restrict__ b2, float* __restrict__ out2,
    const int* __restrict__ lengths,
    int M, int N, int K, int nsplit, int mode) {
    const int m0 = blockIdx.y * 64;
    if ((m0 & 511) >= lengths[m0 >> 9]) return;  // uniform per block; rows unread
    __shared__ __align__(16) short Abh[2][2048];
    __shared__ __align__(16) short Abl[2][2048];
    __shared__ __align__(16) short Bbh[2][2048];
    __shared__ __align__(16) short Bbl[2][2048];
    const int tid = threadIdx.x;
    int bx = blockIdx.x;
    const float* W = W1; const float* bias = b1; float* out = out1;
    int n0;
    if (bx < nsplit) {
        n0 = bx * 64;
    } else {
        W = W2; bias = b2; out = out2;
        n0 = (bx - nsplit) * 64;
    }
    const int wave = tid >> 6;
    const int lane = tid & 63;
    const int mrow = lane & 15;
    const int quad = lane >> 4;
    const int wm = (wave >> 1) * 32;
    const int wn = (wave & 1) * 32;

    const int r_ = tid >> 2;
    const int sg = (tid & 3) * 8;

    f32x4 acc[2][2];
#pragma unroll
    for (int mt = 0; mt < 2; mt++)
#pragma unroll
        for (int nt = 0; nt < 2; nt++) acc[mt][nt] = (f32x4){0.f, 0.f, 0.f, 0.f};

    float4 a0 = *(const float4*)(A + (size_t)(m0 + r_) * K + sg);
    float4 a1 = *(const float4*)(A + (size_t)(m0 + r_) * K + sg + 4);
    float4 w0 = *(const float4*)(W + (size_t)(n0 + r_) * K + sg);
    float4 w1 = *(const float4*)(W + (size_t)(n0 + r_) * K + sg + 4);

    for (int k0 = 0; k0 < K; k0 += 32) {
        const int cur = (k0 >> 5) & 1;
        {
            float av[8] = {a0.x, a0.y, a0.z, a0.w, a1.x, a1.y, a1.z, a1.w};
            float wv[8] = {w0.x, w0.y, w0.z, w0.w, w1.x, w1.y, w1.z, w1.w};
            short8 ah, al, bh, bl;
#pragma unroll
            for (int j = 0; j < 8; j++) {
                short h = f2bf(av[j]); ah[j] = h; al[j] = f2bf(av[j] - bf2f(h));
                short g = f2bf(wv[j]); bh[j] = g; bl[j] = f2bf(wv[j] - bf2f(g));
            }
            *(short8*)&Abh[cur][r_ * 32 + sg] = ah;
            *(short8*)&Abl[cur][r_ * 32 + sg] = al;
            *(short8*)&Bbh[cur][r_ * 32 + sg] = bh;
            *(short8*)&Bbl[cur][r_ * 32 + sg] = bl;
        }
        if (k0 + 32 < K) {
            a0 = *(const float4*)(A + (size_t)(m0 + r_) * K + k0 + 32 + sg);
            a1 = *(const float4*)(A + (size_t)(m0 + r_) * K + k0 + 32 + sg + 4);
            w0 = *(const float4*)(W + (size_t)(n0 + r_) * K + k0 + 32 + sg);
            w1 = *(const float4*)(W + (size_t)(n0 + r_) * K + k0 + 32 + sg + 4);
        }
        bar_lds();
        short8 Ah[2], Al[2], Bh[2], Bl[2];
#pragma unroll
        for (int t = 0; t < 2; t++) {
            int ar = (wm + t * 16 + mrow) * 32 + quad * 8;
            int br = (wn + t * 16 + mrow) * 32 + quad * 8;
            Ah[t] = *(const short8*)&Abh[cur][ar];
            Al[t] = *(const short8*)&Abl[cur][ar];
            Bh[t] = *(const short8*)&Bbh[cur][br];
            Bl[t] = *(const short8*)&Bbl[cur][br];
        }
#pragma unroll
        for (int mt = 0; mt < 2; mt++)
#pragma unroll
            for (int nt = 0; nt < 2; nt++) {
                acc[mt][nt] = __builtin_amdgcn_mfma_f32_16x16x32_bf16(Ah[mt], Bh[nt], acc[mt][nt], 0, 0, 0);
                acc[mt][nt] = __builtin_amdgcn_mfma_f32_16x16x32_bf16(Al[mt], Bh[nt], acc[mt][nt], 0, 0, 0);
                acc[mt][nt] = __builtin_amdgcn_mfma_f32_16x16x32_bf16(Ah[mt], Bl[nt], acc[mt][nt], 0, 0, 0);
            }
        bar_lds();
    }
    float bsv[2];
#pragma unroll
    for (int nt = 0; nt < 2; nt++) bsv[nt] = bias[n0 + wn + nt * 16 + mrow];
#pragma unroll
    for (int mt = 0; mt < 2; mt++)
#pragma unroll
        for (int nt = 0; nt < 2; nt++) {
            int n = n0 + wn + nt * 16 + mrow;
#pragma unroll
            for (int r = 0; r < 4; r++) {
                int m = m0 + wm + mt * 16 + quad * 4 + r;
                float val = acc[mt][nt][r] + bsv[nt];
                if (mode == 1) val = fast_sigmoid(val) * A[(size_t)m * K + n];
                out[(size_t)m * N + n] = val;
            }
        }
}

// ---------------- Attention, 8 queries per block (R12, known-good) -------------------
__global__ __launch_bounds__(512) void attn_kernel(
    const float* __restrict__ v, const int* __restrict__ lengths,
    const float* __restrict__ own, const float* __restrict__ comp,
    const float* __restrict__ v_attn, float* __restrict__ inp) {
    const int L = 512, D = 256, H = 128;
    const int b = blockIdx.x >> 6;
    const int q0 = (blockIdx.x & 63) * 8;
    const int len = lengths[b];
    if (q0 >= len) return;
    const int tid = threadIdx.x;
    const float K2E = 2.8853900817779268f;  // 2*log2(e)
    __shared__ __align__(16) float oKT[128 * 8];
    __shared__ float va2s[128];
    __shared__ __align__(16) float scf[512 * 12];
    __shared__ float inv8[8];

    for (int i = tid; i < 1024; i += 512) {
        int qq = i >> 7, hh = i & 127;
        oKT[hh * 8 + qq] = K2E * own[((size_t)(b * L + q0 + qq)) * H + hh];
    }
    if (tid < 128) va2s[tid] = -2.f * v_attn[tid];
    __syncthreads();

    {
        const int k = tid;
        float acc[8];
#pragma unroll
        for (int q = 0; q < 8; q++) acc[q] = 0.f;
        if (k < len) {
            const float* cp = comp + ((size_t)(b * L + k)) * H;
            for (int h = 0; h < 128; h += 4) {
                float4 c4 = *(const float4*)(cp + h);
                const float* cv = (const float*)&c4;
#pragma unroll
                for (int j = 0; j < 4; j++) {
                    float cK = cv[j] * K2E;
                    float va = va2s[h + j];
                    float4 o0 = *(const float4*)&oKT[(h + j) * 8];
                    float4 o1 = *(const float4*)&oKT[(h + j) * 8 + 4];
                    const float* op0 = (const float*)&o0;
                    const float* op1 = (const float*)&o1;
#pragma unroll
                    for (int q = 0; q < 4; q++) {
                        float r = __builtin_amdgcn_rcpf(1.f + exp2f(cK + op0[q]));
                        acc[q] = fmaf(va, r, acc[q]);
                    }
#pragma unroll
                    for (int q = 0; q < 4; q++) {
                        float r = __builtin_amdgcn_rcpf(1.f + exp2f(cK + op1[q]));
                        acc[4 + q] = fmaf(va, r, acc[4 + q]);
                    }
                }
            }
#pragma unroll
            for (int q = 0; q < 8; q++) acc[q] = __expf(acc[q]);  // bounded, no max pass
        }
        *(float4*)&scf[k * 12] = *(float4*)&acc[0];
        *(float4*)&scf[k * 12 + 4] = *(float4*)&acc[4];
    }
    __syncthreads();

    {
        int w = tid >> 6, l = tid & 63;
        float s = 0.f;
#pragma unroll
        for (int kk = 0; kk < 8; kk++) s += scf[(l + kk * 64) * 12 + w];
#pragma unroll
        for (int off = 1; off < 64; off <<= 1) s += __shfl_xor(s, off);
        if (l == 0) inv8[w] = __builtin_amdgcn_rcpf(s);
    }
    __syncthreads();

    {
        const int d = tid & 255;
        const int qh = tid >> 8;
        float c0 = 0.f, c1 = 0.f, c2 = 0.f, c3 = 0.f;
        const float* vb = v + ((size_t)b * L) * D + d;
        for (int k = 0; k < L; k += 2) {
            float v0 = vb[(size_t)k * D];
            float v1 = vb[(size_t)(k + 1) * D];
            float4 s0 = *(const float4*)&scf[k * 12 + qh * 4];
            float4 s1 = *(const float4*)&scf[(k + 1) * 12 + qh * 4];
            c0 += s0.x * v0 + s1.x * v1;
            c1 += s0.y * v0 + s1.y * v1;
            c2 += s0.z * v0 + s1.z * v1;
            c3 += s0.w * v0 + s1.w * v1;
        }
        float cc[4] = {c0, c1, c2, c3};
#pragma unroll
        for (int j = 0; j < 4; j++) {
            int q = q0 + qh * 4 + j;
            size_t row = ((size_t)(b * L + q)) * 512;
            inp[row + 256 + d] = cc[j] * inv8[qh * 4 + j];
            inp[row + d] = v[((size_t)(b * L + q)) * D + d];
        }
    }
}

// ---------------- GRU recurrence: i8 MFMA K=64 (R20 + independent MFMA accs) ---------
// R22 = R20 EXACT (use-free prefetch loads, fold-at-rotate, native exp2 slim chain,
// magic-number RNE quantize, per-step fire-and-forget store — gru 156us, proven) with
// ONE change: the two MFMAs per gate use INDEPENDENT accumulators instead of a
// dependent chain. Removes one full MFMA latency from the per-step serial chain
// (barrier -> ds_read -> MFMA pair -> gate VALU -> ds_write -> barrier); costs 3
// exact integer adds per gate (lane<16 only). Numerically identical.
// R21 lesson encoded: issue-slot cuts (deferred stores, unpredicated body) REGRESS —
// only dependency-chain and load-schedule changes move this kernel.
// h: Q0.13 = hi*64 + lo (two i8 A rows; integer dot EXACT). W_hh: per-row i8 +
// row scale. hbuf: hi at byte 0, lo at byte 192 (word 48 === 16 mod 32): disjoint
// 16-bank halves. Single lgkmcnt-only barrier per step. 8 waves (2/SIMD — R17
// proved 1 wave/SIMD loses ~400cy/step of MFMA<->VALU<->LDS overlap).
__global__ __launch_bounds__(512, 1) void gru_kernel(
    const float* __restrict__ xp_f, const float* __restrict__ xp_b,
    const float* __restrict__ w_hh_f, const float* __restrict__ w_hh_b,
    const float* __restrict__ b_hh_f, const float* __restrict__ b_hh_b,
    const int* __restrict__ lengths, float* __restrict__ out) {
    const int L = 512, H = 128;
    const float LOG2E = 1.4426950408889634f;
    const float TWO_LOG2E = 2.8853900817779268f;
    const int MAGIC_I = 0x4B400000;  // bits of 12582912.0f = 1.5*2^23
    const int dir = blockIdx.x >> 2;
    const int b = blockIdx.x & 3;
    const float* xp = dir ? xp_b : xp_f;
    const float* w_hh = dir ? w_hh_b : w_hh_f;
    const float* b_hh = dir ? b_hh_b : b_hh_f;
    const int tid = threadIdx.x;
    const int wave = tid >> 6;
    const int lane = tid & 63;
    const int mrow = lane & 15;
    const int quad = lane >> 4;
    const int jj = 16 * wave + lane;  // gate dim for lanes lane<16

    // [parity][ h_hi bytes 0..127 | pad | h_lo bytes 192..319 | pad..383 ]
    __shared__ __align__(16) signed char hbufc[2][384];

    // ---- W_hh -> per-row i8 + scale. Lane (mrow,quad) holds B[k=kt*64+quad*16+j][row]
    // for rows g*128 + 16*wave + mrow; row max reduced across the 4 quads via shfl. ----
    int4_t wb[3][2];
    float wsc0, wsc1, wsc2;  // dequant scales with exp2-conversion factors folded in
    {
        float wsl[3];
#pragma unroll
        for (int g = 0; g < 3; g++) {
            int row = g * 128 + 16 * wave + mrow;
            float wv[32];
#pragma unroll
            for (int kt = 0; kt < 2; kt++)
#pragma unroll
                for (int j4 = 0; j4 < 4; j4++) {
                    float4 f4 = *(const float4*)(w_hh + (size_t)row * H + kt * 64 + quad * 16 + j4 * 4);
                    wv[kt * 16 + j4 * 4 + 0] = f4.x;
                    wv[kt * 16 + j4 * 4 + 1] = f4.y;
                    wv[kt * 16 + j4 * 4 + 2] = f4.z;
                    wv[kt * 16 + j4 * 4 + 3] = f4.w;
                }
            float mx = 0.f;
#pragma unroll
            for (int j = 0; j < 32; j++) mx = fmaxf(mx, fabsf(wv[j]));
            mx = fmaxf(mx, __shfl_xor(mx, 16));
            mx = fmaxf(mx, __shfl_xor(mx, 32));
            mx = fmaxf(mx, 1e-30f);
            float inv_s = 127.f / mx;
            wsl[g] = (mx / 127.f) * (1.f / 8192.f);
#pragma unroll
            for (int kt = 0; kt < 2; kt++) {
                int tmp[4] = {0, 0, 0, 0};
#pragma unroll
                for (int j = 0; j < 16; j++) {
                    int q = (int)rintf(wv[kt * 16 + j] * inv_s);
                    tmp[j >> 2] |= (q & 0xff) << ((j & 3) * 8);
                }
                wb[g][kt] = (int4_t){tmp[0], tmp[1], tmp[2], tmp[3]};
            }
        }
        // fold exp2 conversion: r,z use -(arg)*log2e ; n uses (arg)*2log2e
        wsc0 = -wsl[0] * LOG2E;
        wsc1 = -wsl[1] * LOG2E;
        wsc2 = wsl[2] * TWO_LOG2E;
    }
    float brl = 0.f, bzl = 0.f, bnc = 0.f, hcur = 0.f;
    if (lane < 16) {
        brl = -b_hh[jj] * LOG2E;
        bzl = -b_hh[128 + jj] * LOG2E;
        bnc = b_hh[256 + jj] * TWO_LOG2E;
    }

    const int len = lengths[b];
    // pre-zero masked tail: out[b, t, dir*128+k] = 0 for t in [len, L)
    for (int i = tid; i < (L - len) * 128; i += 512) {
        int tt = len + (i >> 7);
        int kk = i & 127;
        out[((size_t)(b * L + tt)) * 256 + dir * 128 + kk] = 0.f;
    }
    for (int i = tid; i < 768; i += 512) ((signed char*)hbufc)[i] = 0;

    const int nch = (len + 15) >> 4;
    // gate-lane xp registers for the current chunk: RAW loads (use-free, R16-exact),
    // then fold bias + exp2-conversion in place (one-time; off the step chain).
    float xr[16], xz[16], xn[16];
    if (lane < 16) {
#pragma unroll
        for (int s = 0; s < 16; s++) {
            if (s < len) {
                int t = dir ? (len - 1 - s) : s;
                size_t base = ((size_t)(b * L + t)) * 384;
                xr[s] = xp[base + jj];
                xz[s] = xp[base + 128 + jj];
                xn[s] = xp[base + 256 + jj];
            }
        }
#pragma unroll
        for (int s = 0; s < 16; s++) {
            xr[s] = fmaf(xr[s], -LOG2E, brl);
            xz[s] = fmaf(xz[s], -LOG2E, bzl);
            xn[s] = xn[s] * TWO_LOG2E;
        }
    }
    __syncthreads();

    // A-frag byte base: row0 (h_hi) at 0, row1 (h_lo) at 192; rows 2-15 duplicates
    const int bbase = ((mrow & 1) ? 192 : 0) + quad * 16;
    int par = 0;

    for (int c = 0; c < nch; c++) {
        const int cnt = min(16, len - c * 16);
        // prefetch chunk c+1 into a second register set (RAW loads, no use here);
        // vmcnt waits land at the rotate, a full chunk (~12000 cy) later
        float nxr[16], nxz[16], nxn[16];
        if (lane < 16 && c + 1 < nch) {
#pragma unroll
            for (int s = 0; s < 16; s++) {
                int rr = (c + 1) * 16 + s;
                if (rr < len) {
                    int t = dir ? (len - 1 - rr) : rr;
                    size_t base = ((size_t)(b * L + t)) * 384;
                    nxr[s] = xp[base + jj];
                    nxz[s] = xp[base + 128 + jj];
                    nxn[s] = xp[base + 256 + jj];
                }
            }
        }
#pragma unroll
        for (int s = 0; s < 16; s++) {
            if (s < cnt) {  // cnt uniform per block -> barrier counts match
                int4_t af0 = *(const int4_t*)&hbufc[par][bbase];
                int4_t af1 = *(const int4_t*)&hbufc[par][bbase + 64];
                const int4_t z4 = (int4_t){0, 0, 0, 0};
                // independent accumulators: both MFMAs of a gate issue without the
                // second waiting on the first (R22 cut); integer sum restored below.
                int4_t a0  = __builtin_amdgcn_mfma_i32_16x16x64_i8(af0, wb[0][0], z4, 0, 0, 0);
                int4_t a0b = __builtin_amdgcn_mfma_i32_16x16x64_i8(af1, wb[0][1], z4, 0, 0, 0);
                int4_t a1  = __builtin_amdgcn_mfma_i32_16x16x64_i8(af0, wb[1][0], z4, 0, 0, 0);
                int4_t a1b = __builtin_amdgcn_mfma_i32_16x16x64_i8(af1, wb[1][1], z4, 0, 0, 0);
                int4_t a2  = __builtin_amdgcn_mfma_i32_16x16x64_i8(af0, wb[2][0], z4, 0, 0, 0);
                int4_t a2b = __builtin_amdgcn_mfma_i32_16x16x64_i8(af1, wb[2][1], z4, 0, 0, 0);
                if (lane < 16) {
                    // C rows 0/1 (regs 0/1) = W.h_hi / W.h_lo integer dots; h13 = hi*64+lo
                    float drf = (float)((a0[0] + a0b[0]) * 64 + a0[1] + a0b[1]);
                    float dzf = (float)((a1[0] + a1b[0]) * 64 + a1[1] + a1b[1]);
                    float dnf = (float)((a2[0] + a2b[0]) * 64 + a2[1] + a2b[1]);
                    float r = __builtin_amdgcn_rcpf(1.f + __builtin_amdgcn_exp2f(fmaf(drf, wsc0, xr[s])));
                    float z = __builtin_amdgcn_rcpf(1.f + __builtin_amdgcn_exp2f(fmaf(dzf, wsc1, xz[s])));
                    float hh = fmaf(dnf, wsc2, bnc);
                    float n = fmaf(-2.f, __builtin_amdgcn_rcpf(1.f + __builtin_amdgcn_exp2f(fmaf(r, hh, xn[s]))), 1.f);
                    float hn = fmaf(z, hcur - n, n);
                    hcur = hn;
                    // magic-number RNE quantize to Q0.13; integer clamp to +-8191
                    int bi = __float_as_int(fmaf(hn, 8192.f, 12582912.f));
                    bi = min(max(bi, MAGIC_I - 8191), MAGIC_I + 8191);
                    hbufc[par ^ 1][jj] = (signed char)(bi >> 6);        // hi = h13>>6 (arith)
                    hbufc[par ^ 1][192 + jj] = (signed char)(bi & 63);  // lo = h13 mod 64
                    int t = dir ? (len - 1 - (c * 16 + s)) : (c * 16 + s);
                    out[((size_t)(b * L + t)) * 256 + dir * 128 + jj] = hn;  // fire-and-forget
                }
                par ^= 1;
                bar_lds();  // hbufc[par] ready; single barrier per step; vmcnt untouched
            }
        }
        // rotate prefetched chunk into place WITH folding (vmcnt wait lands here,
        // a full chunk later; the 48 fmas are once-per-chunk, off the step chain)
        if (lane < 16 && c + 1 < nch) {
#pragma unroll
            for (int s = 0; s < 16; s++) {
                xr[s] = fmaf(nxr[s], -LOG2E, brl);
                xz[s] = fmaf(nxz[s], -LOG2E, bzl);
                xn[s] = nxn[s] * TWO_LOG2E;
            }
        }
    }
}

extern "C" void kernel_launch(void* const* d_in, const int* in_sizes, int n_in,
                              void* d_out, int out_size, void* d_ws, size_t ws_size,
                              hipStream_t stream) {
    const int B = 4, L = 512, D = 256, H = 128;
    const int M = B * L;  // 2048

    const float* v      = (const float*)d_in[0];
    const int* lengths  = (const int*)d_in[1];
    const float* own_W  = (const float*)d_in[3];
    const float* own_b  = (const float*)d_in[4];
    const float* comp_W = (const float*)d_in[5];
    const float* comp_b = (const float*)d_in[6];
    const float* v_attn = (const float*)d_in[7];
    const float* gate_W = (const float*)d_in[8];
    const float* gate_b = (const float*)d_in[9];
    const float* w_ih_f = (const float*)d_in[10];
    const float* w_hh_f = (const float*)d_in[11];
    const float* b_ih_f = (const float*)d_in[12];
    const float* b_hh_f = (const float*)d_in[13];
    const float* w_ih_b = (const float*)d_in[14];
    const float* w_hh_b = (const float*)d_in[15];
    const float* b_ih_b = (const float*)d_in[16];
    const float* b_hh_b = (const float*)d_in[17];

    float* ws   = (float*)d_ws;
    float* own  = ws;                       // [2048,128]
    float* comp = own + (size_t)M * H;      // [2048,128]
    float* inp  = comp + (size_t)M * H;     // [2048,512]
    float* gated = inp + (size_t)M * 512;   // [2048,512]
    float* xp_f = gated + (size_t)M * 512;  // [2048,384]
    float* xp_b = xp_f + (size_t)M * 384;   // [2048,384]
    float* out  = (float*)d_out;            // [2048,256]

    // 1: own & comp projections in one launch (tiles 0..1 -> own, 2..3 -> comp)
    gemm_bias<<<dim3(4, M / 64), 256, 0, stream>>>(
        v, own_W, own_b, own, comp_W, comp_b, comp, lengths, M, H, D, 2, 0);
    // 2: attention (8 q per block) -> inp = [v, C]
    attn_kernel<<<dim3(B * 64), 512, 0, stream>>>(v, lengths, own, comp, v_attn, inp);
    // 3: gate
    gemm_bias<<<dim3(8, M / 64), 256, 0, stream>>>(
        inp, gate_W, gate_b, gated, gate_W, gate_b, gated, lengths, M, 512, 512, 8, 1);
    // 4: input projections for both GRU directions in one launch
    gemm_bias<<<dim3(12, M / 64), 256, 0, stream>>>(
        gated, w_ih_f, b_ih_f, xp_f, w_ih_b, b_ih_b, xp_b, lengths, M, 384, 512, 6, 0);
    // 5: sequential GRU, one block per (dir, batch), 8 waves (2/SIMD)
    gru_kernel<<<dim3(8), 512, 0, stream>>>(xp_f, xp_b, w_hh_f, w_hh_b, b_hh_f, b_hh_b, lengths, out);
}

// Round 8
// 344.410 us; speedup vs baseline: 1.0167x; 1.0078x over previous
//
#include <hip/hip_runtime.h>
#include <hip/hip_bf16.h>

#define NEGINF -1e30f

typedef __attribute__((ext_vector_type(8))) short short8;
typedef __attribute__((ext_vector_type(4))) float f32x4;
typedef __attribute__((ext_vector_type(4))) int int4_t;

// Clamp-free: IEEE inf semantics give exact limits (exp->inf => rcp->0), NaN-free.
__device__ __forceinline__ float fast_sigmoid(float x) {
    return __builtin_amdgcn_rcpf(1.f + __expf(-x));
}
// round-to-nearest-even f32 -> bf16 bits
__device__ __forceinline__ short f2bf(float f) {
    unsigned u = __float_as_uint(f);
    return (short)((u + 0x7fff + ((u >> 16) & 1)) >> 16);
}
__device__ __forceinline__ float bf2f(short b) {
    return __uint_as_float(((unsigned)(unsigned short)b) << 16);
}

// LDS-only workgroup barrier (proven R3-R20): waits lgkmcnt only; in-flight global
// loads/stores are NOT drained. Safe when all cross-thread traffic goes through LDS.
__device__ __forceinline__ void bar_lds() {
    asm volatile("s_waitcnt lgkmcnt(0)\n\ts_barrier" ::: "memory");
}

// ---------------- MFMA GEMM (R12, known-good): out = A @ W^T + bias ------------------
__global__ __launch_bounds__(256) void gemm_bias(
    const float* __restrict__ A,
    const float* __restrict__ W1, const float* __restrict__ b1, float* __restrict__ out1,
    const float* __restrict__ W2, const float* __restrict__ b2, float* __restrict__ out2,
    const int* __restrict__ lengths,
    int M, int N, int K, int nsplit, int mode) {
    const int m0 = blockIdx.y * 64;
    if ((m0 & 511) >= lengths[m0 >> 9]) return;  // uniform per block; rows unread
    __shared__ __align__(16) short Abh[2][2048];
    __shared__ __align__(16) short Abl[2][2048];
    __shared__ __align__(16) short Bbh[2][2048];
    __shared__ __align__(16) short Bbl[2][2048];
    const int tid = threadIdx.x;
    int bx = blockIdx.x;
    const float* W = W1; const float* bias = b1; float* out = out1;
    int n0;
    if (bx < nsplit) {
        n0 = bx * 64;
    } else {
        W = W2; bias = b2; out = out2;
        n0 = (bx - nsplit) * 64;
    }
    const int wave = tid >> 6;
    const int lane = tid & 63;
    const int mrow = lane & 15;
    const int quad = lane >> 4;
    const int wm = (wave >> 1) * 32;
    const int wn = (wave & 1) * 32;

    const int r_ = tid >> 2;
    const int sg = (tid & 3) * 8;

    f32x4 acc[2][2];
#pragma unroll
    for (int mt = 0; mt < 2; mt++)
#pragma unroll
        for (int nt = 0; nt < 2; nt++) acc[mt][nt] = (f32x4){0.f, 0.f, 0.f, 0.f};

    float4 a0 = *(const float4*)(A + (size_t)(m0 + r_) * K + sg);
    float4 a1 = *(const float4*)(A + (size_t)(m0 + r_) * K + sg + 4);
    float4 w0 = *(const float4*)(W + (size_t)(n0 + r_) * K + sg);
    float4 w1 = *(const float4*)(W + (size_t)(n0 + r_) * K + sg + 4);

    for (int k0 = 0; k0 < K; k0 += 32) {
        const int cur = (k0 >> 5) & 1;
        {
            float av[8] = {a0.x, a0.y, a0.z, a0.w, a1.x, a1.y, a1.z, a1.w};
            float wv[8] = {w0.x, w0.y, w0.z, w0.w, w1.x, w1.y, w1.z, w1.w};
            short8 ah, al, bh, bl;
#pragma unroll
            for (int j = 0; j < 8; j++) {
                short h = f2bf(av[j]); ah[j] = h; al[j] = f2bf(av[j] - bf2f(h));
                short g = f2bf(wv[j]); bh[j] = g; bl[j] = f2bf(wv[j] - bf2f(g));
            }
            *(short8*)&Abh[cur][r_ * 32 + sg] = ah;
            *(short8*)&Abl[cur][r_ * 32 + sg] = al;
            *(short8*)&Bbh[cur][r_ * 32 + sg] = bh;
            *(short8*)&Bbl[cur][r_ * 32 + sg] = bl;
        }
        if (k0 + 32 < K) {
            a0 = *(const float4*)(A + (size_t)(m0 + r_) * K + k0 + 32 + sg);
            a1 = *(const float4*)(A + (size_t)(m0 + r_) * K + k0 + 32 + sg + 4);
            w0 = *(const float4*)(W + (size_t)(n0 + r_) * K + k0 + 32 + sg);
            w1 = *(const float4*)(W + (size_t)(n0 + r_) * K + k0 + 32 + sg + 4);
        }
        bar_lds();
        short8 Ah[2], Al[2], Bh[2], Bl[2];
#pragma unroll
        for (int t = 0; t < 2; t++) {
            int ar = (wm + t * 16 + mrow) * 32 + quad * 8;
            int br = (wn + t * 16 + mrow) * 32 + quad * 8;
            Ah[t] = *(const short8*)&Abh[cur][ar];
            Al[t] = *(const short8*)&Abl[cur][ar];
            Bh[t] = *(const short8*)&Bbh[cur][br];
            Bl[t] = *(const short8*)&Bbl[cur][br];
        }
#pragma unroll
        for (int mt = 0; mt < 2; mt++)
#pragma unroll
            for (int nt = 0; nt < 2; nt++) {
                acc[mt][nt] = __builtin_amdgcn_mfma_f32_16x16x32_bf16(Ah[mt], Bh[nt], acc[mt][nt], 0, 0, 0);
                acc[mt][nt] = __builtin_amdgcn_mfma_f32_16x16x32_bf16(Al[mt], Bh[nt], acc[mt][nt], 0, 0, 0);
                acc[mt][nt] = __builtin_amdgcn_mfma_f32_16x16x32_bf16(Ah[mt], Bl[nt], acc[mt][nt], 0, 0, 0);
            }
        bar_lds();
    }
    float bsv[2];
#pragma unroll
    for (int nt = 0; nt < 2; nt++) bsv[nt] = bias[n0 + wn + nt * 16 + mrow];
#pragma unroll
    for (int mt = 0; mt < 2; mt++)
#pragma unroll
        for (int nt = 0; nt < 2; nt++) {
            int n = n0 + wn + nt * 16 + mrow;
#pragma unroll
            for (int r = 0; r < 4; r++) {
                int m = m0 + wm + mt * 16 + quad * 4 + r;
                float val = acc[mt][nt][r] + bsv[nt];
                if (mode == 1) val = fast_sigmoid(val) * A[(size_t)m * K + n];
                out[(size_t)m * N + n] = val;
            }
        }
}

// ---------------- Attention, 8 queries per block (R12, known-good) -------------------
__global__ __launch_bounds__(512) void attn_kernel(
    const float* __restrict__ v, const int* __restrict__ lengths,
    const float* __restrict__ own, const float* __restrict__ comp,
    const float* __restrict__ v_attn, float* __restrict__ inp) {
    const int L = 512, D = 256, H = 128;
    const int b = blockIdx.x >> 6;
    const int q0 = (blockIdx.x & 63) * 8;
    const int len = lengths[b];
    if (q0 >= len) return;
    const int tid = threadIdx.x;
    const float K2E = 2.8853900817779268f;  // 2*log2(e)
    __shared__ __align__(16) float oKT[128 * 8];
    __shared__ float va2s[128];
    __shared__ __align__(16) float scf[512 * 12];
    __shared__ float inv8[8];

    for (int i = tid; i < 1024; i += 512) {
        int qq = i >> 7, hh = i & 127;
        oKT[hh * 8 + qq] = K2E * own[((size_t)(b * L + q0 + qq)) * H + hh];
    }
    if (tid < 128) va2s[tid] = -2.f * v_attn[tid];
    __syncthreads();

    {
        const int k = tid;
        float acc[8];
#pragma unroll
        for (int q = 0; q < 8; q++) acc[q] = 0.f;
        if (k < len) {
            const float* cp = comp + ((size_t)(b * L + k)) * H;
            for (int h = 0; h < 128; h += 4) {
                float4 c4 = *(const float4*)(cp + h);
                const float* cv = (const float*)&c4;
#pragma unroll
                for (int j = 0; j < 4; j++) {
                    float cK = cv[j] * K2E;
                    float va = va2s[h + j];
                    float4 o0 = *(const float4*)&oKT[(h + j) * 8];
                    float4 o1 = *(const float4*)&oKT[(h + j) * 8 + 4];
                    const float* op0 = (const float*)&o0;
                    const float* op1 = (const float*)&o1;
#pragma unroll
                    for (int q = 0; q < 4; q++) {
                        float r = __builtin_amdgcn_rcpf(1.f + exp2f(cK + op0[q]));
                        acc[q] = fmaf(va, r, acc[q]);
                    }
#pragma unroll
                    for (int q = 0; q < 4; q++) {
                        float r = __builtin_amdgcn_rcpf(1.f + exp2f(cK + op1[q]));
                        acc[4 + q] = fmaf(va, r, acc[4 + q]);
                    }
                }
            }
#pragma unroll
            for (int q = 0; q < 8; q++) acc[q] = __expf(acc[q]);  // bounded, no max pass
        }
        *(float4*)&scf[k * 12] = *(float4*)&acc[0];
        *(float4*)&scf[k * 12 + 4] = *(float4*)&acc[4];
    }
    __syncthreads();

    {
        int w = tid >> 6, l = tid & 63;
        float s = 0.f;
#pragma unroll
        for (int kk = 0; kk < 8; kk++) s += scf[(l + kk * 64) * 12 + w];
#pragma unroll
        for (int off = 1; off < 64; off <<= 1) s += __shfl_xor(s, off);
        if (l == 0) inv8[w] = __builtin_amdgcn_rcpf(s);
    }
    __syncthreads();

    {
        const int d = tid & 255;
        const int qh = tid >> 8;
        float c0 = 0.f, c1 = 0.f, c2 = 0.f, c3 = 0.f;
        const float* vb = v + ((size_t)b * L) * D + d;
        for (int k = 0; k < L; k += 2) {
            float v0 = vb[(size_t)k * D];
            float v1 = vb[(size_t)(k + 1) * D];
            float4 s0 = *(const float4*)&scf[k * 12 + qh * 4];
            float4 s1 = *(const float4*)&scf[(k + 1) * 12 + qh * 4];
            c0 += s0.x * v0 + s1.x * v1;
            c1 += s0.y * v0 + s1.y * v1;
            c2 += s0.z * v0 + s1.z * v1;
            c3 += s0.w * v0 + s1.w * v1;
        }
        float cc[4] = {c0, c1, c2, c3};
#pragma unroll
        for (int j = 0; j < 4; j++) {
            int q = q0 + qh * 4 + j;
            size_t row = ((size_t)(b * L + q)) * 512;
            inp[row + 256 + d] = cc[j] * inv8[qh * 4 + j];
            inp[row + d] = v[((size_t)(b * L + q)) * D + d];
        }
    }
}

// ---------------- GRU recurrence: i8 MFMA K=64 (R20 FINAL — session best) ------------
// R23 = R20 byte-exact revert (gru 156.2us, e2e 345.4us). The verified structure:
//  - R16 load schedule: prefetch loads are RAW and use-free; first use is the rotate
//    a full chunk (~12000 cy) later, so vmcnt waits never land on the serial path.
//    (R18/R19 proved folding at the load site costs ~80us; R20 proved the fix.)
//  - Folding (log2e+bias into xp) at the ROTATE, once per chunk, off the step chain.
//  - Slim on-chain math: native exp2 (v_exp_f32) with pre-folded constants;
//    magic-number RNE quantize (fma to 1.5*2^23 + int clamp + byte extract).
//  - Dependent MFMA pairs per gate (R22 proved independent accumulators LOSE ~14us:
//    three gate chains already fill the pipe; the split only adds VALU+VGPR).
//  - Per-step fire-and-forget store (R21 proved deferring stores LOSES ~7us).
// h: Q0.13 = hi*64 + lo (two i8 A rows; integer dot EXACT). W_hh: per-row i8 +
// row scale. hbuf: hi at byte 0, lo at byte 192 (word 48 === 16 mod 32): disjoint
// 16-bank halves. Single lgkmcnt-only barrier per step. 8 waves (2/SIMD — R17
// proved 1 wave/SIMD loses ~400cy/step of MFMA<->VALU<->LDS overlap).
// Remaining time is the irreducible serial loop: quantize -> ds_write -> barrier ->
// ds_read -> MFMA -> gate transcendental chain, ~742 cy x ~510 steps.
__global__ __launch_bounds__(512, 1) void gru_kernel(
    const float* __restrict__ xp_f, const float* __restrict__ xp_b,
    const float* __restrict__ w_hh_f, const float* __restrict__ w_hh_b,
    const float* __restrict__ b_hh_f, const float* __restrict__ b_hh_b,
    const int* __restrict__ lengths, float* __restrict__ out) {
    const int L = 512, H = 128;
    const float LOG2E = 1.4426950408889634f;
    const float TWO_LOG2E = 2.8853900817779268f;
    const int MAGIC_I = 0x4B400000;  // bits of 12582912.0f = 1.5*2^23
    const int dir = blockIdx.x >> 2;
    const int b = blockIdx.x & 3;
    const float* xp = dir ? xp_b : xp_f;
    const float* w_hh = dir ? w_hh_b : w_hh_f;
    const float* b_hh = dir ? b_hh_b : b_hh_f;
    const int tid = threadIdx.x;
    const int wave = tid >> 6;
    const int lane = tid & 63;
    const int mrow = lane & 15;
    const int quad = lane >> 4;
    const int jj = 16 * wave + lane;  // gate dim for lanes lane<16

    // [parity][ h_hi bytes 0..127 | pad | h_lo bytes 192..319 | pad..383 ]
    __shared__ __align__(16) signed char hbufc[2][384];

    // ---- W_hh -> per-row i8 + scale. Lane (mrow,quad) holds B[k=kt*64+quad*16+j][row]
    // for rows g*128 + 16*wave + mrow; row max reduced across the 4 quads via shfl. ----
    int4_t wb[3][2];
    float wsc0, wsc1, wsc2;  // dequant scales with exp2-conversion factors folded in
    {
        float wsl[3];
#pragma unroll
        for (int g = 0; g < 3; g++) {
            int row = g * 128 + 16 * wave + mrow;
            float wv[32];
#pragma unroll
            for (int kt = 0; kt < 2; kt++)
#pragma unroll
                for (int j4 = 0; j4 < 4; j4++) {
                    float4 f4 = *(const float4*)(w_hh + (size_t)row * H + kt * 64 + quad * 16 + j4 * 4);
                    wv[kt * 16 + j4 * 4 + 0] = f4.x;
                    wv[kt * 16 + j4 * 4 + 1] = f4.y;
                    wv[kt * 16 + j4 * 4 + 2] = f4.z;
                    wv[kt * 16 + j4 * 4 + 3] = f4.w;
                }
            float mx = 0.f;
#pragma unroll
            for (int j = 0; j < 32; j++) mx = fmaxf(mx, fabsf(wv[j]));
            mx = fmaxf(mx, __shfl_xor(mx, 16));
            mx = fmaxf(mx, __shfl_xor(mx, 32));
            mx = fmaxf(mx, 1e-30f);
            float inv_s = 127.f / mx;
            wsl[g] = (mx / 127.f) * (1.f / 8192.f);
#pragma unroll
            for (int kt = 0; kt < 2; kt++) {
                int tmp[4] = {0, 0, 0, 0};
#pragma unroll
                for (int j = 0; j < 16; j++) {
                    int q = (int)rintf(wv[kt * 16 + j] * inv_s);
                    tmp[j >> 2] |= (q & 0xff) << ((j & 3) * 8);
                }
                wb[g][kt] = (int4_t){tmp[0], tmp[1], tmp[2], tmp[3]};
            }
        }
        // fold exp2 conversion: r,z use -(arg)*log2e ; n uses (arg)*2log2e
        wsc0 = -wsl[0] * LOG2E;
        wsc1 = -wsl[1] * LOG2E;
        wsc2 = wsl[2] * TWO_LOG2E;
    }
    float brl = 0.f, bzl = 0.f, bnc = 0.f, hcur = 0.f;
    if (lane < 16) {
        brl = -b_hh[jj] * LOG2E;
        bzl = -b_hh[128 + jj] * LOG2E;
        bnc = b_hh[256 + jj] * TWO_LOG2E;
    }

    const int len = lengths[b];
    // pre-zero masked tail: out[b, t, dir*128+k] = 0 for t in [len, L)
    for (int i = tid; i < (L - len) * 128; i += 512) {
        int tt = len + (i >> 7);
        int kk = i & 127;
        out[((size_t)(b * L + tt)) * 256 + dir * 128 + kk] = 0.f;
    }
    for (int i = tid; i < 768; i += 512) ((signed char*)hbufc)[i] = 0;

    const int nch = (len + 15) >> 4;
    // gate-lane xp registers for the current chunk: RAW loads (use-free, R16-exact),
    // then fold bias + exp2-conversion in place (one-time; off the step chain).
    float xr[16], xz[16], xn[16];
    if (lane < 16) {
#pragma unroll
        for (int s = 0; s < 16; s++) {
            if (s < len) {
                int t = dir ? (len - 1 - s) : s;
                size_t base = ((size_t)(b * L + t)) * 384;
                xr[s] = xp[base + jj];
                xz[s] = xp[base + 128 + jj];
                xn[s] = xp[base + 256 + jj];
            }
        }
#pragma unroll
        for (int s = 0; s < 16; s++) {
            xr[s] = fmaf(xr[s], -LOG2E, brl);
            xz[s] = fmaf(xz[s], -LOG2E, bzl);
            xn[s] = xn[s] * TWO_LOG2E;
        }
    }
    __syncthreads();

    // A-frag byte base: row0 (h_hi) at 0, row1 (h_lo) at 192; rows 2-15 duplicates
    const int bbase = ((mrow & 1) ? 192 : 0) + quad * 16;
    int par = 0;

    for (int c = 0; c < nch; c++) {
        const int cnt = min(16, len - c * 16);
        // prefetch chunk c+1 into a second register set (RAW loads, no use here);
        // vmcnt waits land at the rotate, a full chunk (~12000 cy) later
        float nxr[16], nxz[16], nxn[16];
        if (lane < 16 && c + 1 < nch) {
#pragma unroll
            for (int s = 0; s < 16; s++) {
                int rr = (c + 1) * 16 + s;
                if (rr < len) {
                    int t = dir ? (len - 1 - rr) : rr;
                    size_t base = ((size_t)(b * L + t)) * 384;
                    nxr[s] = xp[base + jj];
                    nxz[s] = xp[base + 128 + jj];
                    nxn[s] = xp[base + 256 + jj];
                }
            }
        }
#pragma unroll
        for (int s = 0; s < 16; s++) {
            if (s < cnt) {  // cnt uniform per block -> barrier counts match
                int4_t af0 = *(const int4_t*)&hbufc[par][bbase];
                int4_t af1 = *(const int4_t*)&hbufc[par][bbase + 64];
                int4_t a0 = (int4_t){0, 0, 0, 0};
                int4_t a1 = (int4_t){0, 0, 0, 0};
                int4_t a2 = (int4_t){0, 0, 0, 0};
                // g-major: a0 (r) complete after 2, a1 (z) after 4, a2 (n) last
                a0 = __builtin_amdgcn_mfma_i32_16x16x64_i8(af0, wb[0][0], a0, 0, 0, 0);
                a0 = __builtin_amdgcn_mfma_i32_16x16x64_i8(af1, wb[0][1], a0, 0, 0, 0);
                a1 = __builtin_amdgcn_mfma_i32_16x16x64_i8(af0, wb[1][0], a1, 0, 0, 0);
                a1 = __builtin_amdgcn_mfma_i32_16x16x64_i8(af1, wb[1][1], a1, 0, 0, 0);
                a2 = __builtin_amdgcn_mfma_i32_16x16x64_i8(af0, wb[2][0], a2, 0, 0, 0);
                a2 = __builtin_amdgcn_mfma_i32_16x16x64_i8(af1, wb[2][1], a2, 0, 0, 0);
                if (lane < 16) {
                    // C rows 0/1 (regs 0/1) = W.h_hi / W.h_lo integer dots; h13 = hi*64+lo
                    float drf = (float)(a0[0] * 64 + a0[1]);
                    float dzf = (float)(a1[0] * 64 + a1[1]);
                    float dnf = (float)(a2[0] * 64 + a2[1]);
                    float r = __builtin_amdgcn_rcpf(1.f + __builtin_amdgcn_exp2f(fmaf(drf, wsc0, xr[s])));
                    float z = __builtin_amdgcn_rcpf(1.f + __builtin_amdgcn_exp2f(fmaf(dzf, wsc1, xz[s])));
                    float hh = fmaf(dnf, wsc2, bnc);
                    float n = fmaf(-2.f, __builtin_amdgcn_rcpf(1.f + __builtin_amdgcn_exp2f(fmaf(r, hh, xn[s]))), 1.f);
                    float hn = fmaf(z, hcur - n, n);
                    hcur = hn;
                    // magic-number RNE quantize to Q0.13; integer clamp to +-8191
                    int bi = __float_as_int(fmaf(hn, 8192.f, 12582912.f));
                    bi = min(max(bi, MAGIC_I - 8191), MAGIC_I + 8191);
                    hbufc[par ^ 1][jj] = (signed char)(bi >> 6);        // hi = h13>>6 (arith)
                    hbufc[par ^ 1][192 + jj] = (signed char)(bi & 63);  // lo = h13 mod 64
                    int t = dir ? (len - 1 - (c * 16 + s)) : (c * 16 + s);
                    out[((size_t)(b * L + t)) * 256 + dir * 128 + jj] = hn;  // fire-and-forget
                }
                par ^= 1;
                bar_lds();  // hbufc[par] ready; single barrier per step; vmcnt untouched
            }
        }
        // rotate prefetched chunk into place WITH folding (vmcnt wait lands here,
        // a full chunk later; the 48 fmas are once-per-chunk, off the step chain)
        if (lane < 16 && c + 1 < nch) {
#pragma unroll
            for (int s = 0; s < 16; s++) {
                xr[s] = fmaf(nxr[s], -LOG2E, brl);
                xz[s] = fmaf(nxz[s], -LOG2E, bzl);
                xn[s] = nxn[s] * TWO_LOG2E;
            }
        }
    }
}

extern "C" void kernel_launch(void* const* d_in, const int* in_sizes, int n_in,
                              void* d_out, int out_size, void* d_ws, size_t ws_size,
                              hipStream_t stream) {
    const int B = 4, L = 512, D = 256, H = 128;
    const int M = B * L;  // 2048

    const float* v      = (const float*)d_in[0];
    const int* lengths  = (const int*)d_in[1];
    const float* own_W  = (const float*)d_in[3];
    const float* own_b  = (const float*)d_in[4];
    const float* comp_W = (const float*)d_in[5];
    const float* comp_b = (const float*)d_in[6];
    const float* v_attn = (const float*)d_in[7];
    const float* gate_W = (const float*)d_in[8];
    const float* gate_b = (const float*)d_in[9];
    const float* w_ih_f = (const float*)d_in[10];
    const float* w_hh_f = (const float*)d_in[11];
    const float* b_ih_f = (const float*)d_in[12];
    const float* b_hh_f = (const float*)d_in[13];
    const float* w_ih_b = (const float*)d_in[14];
    const float* w_hh_b = (const float*)d_in[15];
    const float* b_ih_b = (const float*)d_in[16];
    const float* b_hh_b = (const float*)d_in[17];

    float* ws   = (float*)d_ws;
    float* own  = ws;                       // [2048,128]
    float* comp = own + (size_t)M * H;      // [2048,128]
    float* inp  = comp + (size_t)M * H;     // [2048,512]
    float* gated = inp + (size_t)M * 512;   // [2048,512]
    float* xp_f = gated + (size_t)M * 512;  // [2048,384]
    float* xp_b = xp_f + (size_t)M * 384;   // [2048,384]
    float* out  = (float*)d_out;            // [2048,256]

    // 1: own & comp projections in one launch (tiles 0..1 -> own, 2..3 -> comp)
    gemm_bias<<<dim3(4, M / 64), 256, 0, stream>>>(
        v, own_W, own_b, own, comp_W, comp_b, comp, lengths, M, H, D, 2, 0);
    // 2: attention (8 q per block) -> inp = [v, C]
    attn_kernel<<<dim3(B * 64), 512, 0, stream>>>(v, lengths, own, comp, v_attn, inp);
    // 3: gate
    gemm_bias<<<dim3(8, M / 64), 256, 0, stream>>>(
        inp, gate_W, gate_b, gated, gate_W, gate_b, gated, lengths, M, 512, 512, 8, 1);
    // 4: input projections for both GRU directions in one launch
    gemm_bias<<<dim3(12, M / 64), 256, 0, stream>>>(
        gated, w_ih_f, b_ih_f, xp_f, w_ih_b, b_ih_b, xp_b, lengths, M, 384, 512, 6, 0);
    // 5: sequential GRU, one block per (dir, batch), 8 waves (2/SIMD)
    gru_kernel<<<dim3(8), 512, 0, stream>>>(xp_f, xp_b, w_hh_f, w_hh_b, b_hh_f, b_hh_b, lengths, out);
}